// Round 1
// baseline (315.500 us; speedup 1.0000x reference)
//
#include <hip/hip_runtime.h>
#include <cmath>

#define T_DIM 2048
#define B_DIM 8
#define C_DIM 1024
#define H_DIM 8
#define R_DIM 128
#define BH_DIM 64          // B*H
#define COLS 8192          // BH*R
#define NCH 32             // scan chunks
#define LT 64              // T per chunk
__device__ __constant__ float INV_K = 0.33333333333333333f;

// ---------------- Phase 1: off = sigmoid(x @ W + b) ----------------
// One wave per row (4 rows/wave, 4 waves/block). W transposed into LDS:
// Wt[j][c] so lane-consecutive c -> conflict-free LDS reads.
__global__ void offsets_kernel(const float* __restrict__ x,
                               const float* __restrict__ W,
                               const float* __restrict__ bias,
                               float* __restrict__ off) {
    __shared__ float Wt[16 * 1024];
    for (int idx = threadIdx.x; idx < 16 * 1024; idx += 256) {
        int j = idx >> 10, c = idx & 1023;
        Wt[idx] = W[c * 16 + j];      // LDS write linear -> conflict-free
    }
    __syncthreads();
    int wave = threadIdx.x >> 6, lane = threadIdx.x & 63;
    int rowBase = blockIdx.x * 16 + wave * 4;
    for (int i = 0; i < 4; ++i) {
        int row = rowBase + i;
        const float* xr = x + (size_t)row * C_DIM;
        float acc[16];
#pragma unroll
        for (int j = 0; j < 16; ++j) acc[j] = 0.f;
        for (int k = 0; k < 16; ++k) {
            int c = lane + k * 64;
            float xv = xr[c];               // coalesced 4B/lane
#pragma unroll
            for (int j = 0; j < 16; ++j)
                acc[j] = fmaf(xv, Wt[j * 1024 + c], acc[j]);
        }
#pragma unroll
        for (int j = 0; j < 16; ++j) {
            float v = acc[j];
#pragma unroll
            for (int o = 1; o < 64; o <<= 1) v += __shfl_xor(v, o, 64);
            acc[j] = v;
        }
        if (lane < 16) {
            float v = 0.f;
#pragma unroll
            for (int j = 0; j < 16; ++j) if (lane == j) v = acc[j];  // static idx only
            v += bias[lane];
            off[(size_t)row * 16 + lane] = 1.f / (1.f + expf(-v));
        }
    }
}

// ---------------- Phase 2a: per-chunk sums ----------------
__global__ void chunksum_kernel(const float* __restrict__ x, float* __restrict__ csum) {
    int gid = blockIdx.x * 256 + threadIdx.x;   // 32*8192 threads
    int chunk = gid >> 13;
    int col = gid & 8191;
    const float* xp = x + (size_t)chunk * LT * COLS + col;
    float s = 0.f;
    for (int t = 0; t < LT; ++t) s += xp[(size_t)t * COLS];
    csum[gid] = s * INV_K;
}

// ---------------- Phase 2b: scan within chunk + write S ----------------
__global__ void scan_kernel(const float* __restrict__ x, const float* __restrict__ csum,
                            float* __restrict__ S) {
    int gid = blockIdx.x * 256 + threadIdx.x;
    int chunk = gid >> 13;                      // uniform within block
    int col = gid & 8191;
    float run = 0.f;
    for (int c = 0; c < chunk; ++c) run += csum[c * COLS + col];  // L2-hot, 1MB
    const float* xp = x + (size_t)chunk * LT * COLS + col;
    float* Sp = S + (size_t)chunk * LT * COLS + col;
    for (int t = 0; t < LT; ++t) {
        run += xp[(size_t)t * COLS] * INV_K;
        Sp[(size_t)t * COLS] = run;             // coalesced
    }
}

// ---------------- Phase 3: interpolated gather ----------------
__device__ __forceinline__ float interp1(const float* __restrict__ S, float f, int col) {
    float ff = floorf(f);
    int i0 = (int)ff;
    float frac = f - ff;
    int i0c = min(max(i0, 0), T_DIM - 1);
    int i1c = min(i0 + 1, T_DIM - 1);           // i0+1 >= 0 since f >= -1
    float v1 = S[(size_t)i1c * COLS + col];
    float v0 = (i0 >= 0) ? S[(size_t)i0c * COLS + col] : 0.f;
    return v0 + frac * (v1 - v0);
}

__global__ void gather_kernel(const float* __restrict__ S, const float* __restrict__ off,
                              float* __restrict__ out) {
    int idx = blockIdx.x * 256 + threadIdx.x;   // < T*B*C
    int r = idx & 127;
    int bh = (idx >> 7) & 63;
    int t = idx >> 13;
    int b = bh >> 3, h = bh & 7;
    const float* o = off + ((size_t)t * B_DIM + b) * 16;
    float aL = o[h], aR = o[8 + h];
    float tf = (float)t;
    float lenL = 1.f + aL * fmaxf(tf - 1.f, 0.f);
    float lenR = 1.f + aR * fmaxf((float)(T_DIM - 1) - tf - 1.f, 0.f);
    float fL = fmaxf(tf - lenL - 1.f, -1.f);
    float fR = fminf(tf + lenR, (float)(T_DIM - 1));
    int col = (bh << 7) | r;
    out[idx] = interp1(S, fR, col) - interp1(S, fL, col);
}

extern "C" void kernel_launch(void* const* d_in, const int* in_sizes, int n_in,
                              void* d_out, int out_size, void* d_ws, size_t ws_size,
                              hipStream_t stream) {
    const float* x = (const float*)d_in[0];
    const float* W = (const float*)d_in[1];
    const float* b = (const float*)d_in[2];
    float* out = (float*)d_out;

    char* ws = (char*)d_ws;
    const size_t S_bytes   = (size_t)T_DIM * COLS * sizeof(float);      // 64 MB
    const size_t off_bytes = (size_t)T_DIM * B_DIM * 16 * sizeof(float); // 1 MB
    float* S    = (float*)ws;
    float* off  = (float*)(ws + S_bytes);
    float* csum = (float*)(ws + S_bytes + off_bytes);                    // 1 MB

    offsets_kernel<<<(T_DIM * B_DIM) / 16, 256, 0, stream>>>(x, W, b, off);
    chunksum_kernel<<<(NCH * COLS) / 256, 256, 0, stream>>>(x, csum);
    scan_kernel<<<(NCH * COLS) / 256, 256, 0, stream>>>(x, csum, S);
    gather_kernel<<<(T_DIM * B_DIM * C_DIM) / 256, 256, 0, stream>>>(S, off, out);
}

// Round 2
// 109.416 us; speedup vs baseline: 2.8835x; 2.8835x over previous
//
#include <hip/hip_runtime.h>
#include <cmath>

#define T_DIM 2048
#define B_DIM 8
#define C_DIM 1024
#define H_DIM 8
#define R_DIM 128
#define BH_DIM 64          // B*H
#define COLS 8192          // BH*R
#define NCH 32             // scan chunks
#define LT 64              // T per chunk
__device__ __constant__ float INV_K = 0.33333333333333333f;

// ---------------- Phase 1: off = sigmoid(x @ W + b) ----------------
// 4 waves/block, 4 rows per wave processed CONCURRENTLY.
// W transposed in LDS as Wt[j][c]; each sweep: 4 float4 x loads + 16
// ds_read_b128 W reads shared across the 4 rows + 256 FMAs.
// Reduction: log2 value-folding (63 shuffles per 4 rows); lane l ends
// holding output (row = l>>4, j = l&15) -> one coalesced 256B store.
__global__ __launch_bounds__(256) void offsets_kernel(
        const float* __restrict__ x, const float* __restrict__ W,
        const float* __restrict__ bias, float* __restrict__ off) {
    __shared__ float Wt[16 * 1024];
    for (int idx = threadIdx.x; idx < 4096; idx += 256) {
        int c = idx >> 2, j4 = (idx & 3) * 4;
        float4 w = *reinterpret_cast<const float4*>(W + c * 16 + j4);
        Wt[(j4 + 0) * 1024 + c] = w.x;
        Wt[(j4 + 1) * 1024 + c] = w.y;
        Wt[(j4 + 2) * 1024 + c] = w.z;
        Wt[(j4 + 3) * 1024 + c] = w.w;
    }
    __syncthreads();

    int wave = threadIdx.x >> 6, lane = threadIdx.x & 63;
    int rowBase = blockIdx.x * 16 + wave * 4;
    const float* xr = x + (size_t)rowBase * C_DIM;

    float v[64];
#pragma unroll
    for (int i = 0; i < 64; ++i) v[i] = 0.f;

#pragma unroll
    for (int k = 0; k < 4; ++k) {
        int c = lane * 4 + k * 256;
        float4 xa = *reinterpret_cast<const float4*>(xr + c);
        float4 xb = *reinterpret_cast<const float4*>(xr + 1024 + c);
        float4 xc = *reinterpret_cast<const float4*>(xr + 2048 + c);
        float4 xd = *reinterpret_cast<const float4*>(xr + 3072 + c);
#pragma unroll
        for (int j = 0; j < 16; ++j) {
            float4 w = *reinterpret_cast<const float4*>(&Wt[j * 1024 + c]);
            v[j]      = fmaf(xa.x, w.x, fmaf(xa.y, w.y, fmaf(xa.z, w.z, fmaf(xa.w, w.w, v[j]))));
            v[16 + j] = fmaf(xb.x, w.x, fmaf(xb.y, w.y, fmaf(xb.z, w.z, fmaf(xb.w, w.w, v[16 + j]))));
            v[32 + j] = fmaf(xc.x, w.x, fmaf(xc.y, w.y, fmaf(xc.z, w.z, fmaf(xc.w, w.w, v[32 + j]))));
            v[48 + j] = fmaf(xd.x, w.x, fmaf(xd.y, w.y, fmaf(xd.z, w.z, fmaf(xd.w, w.w, v[48 + j]))));
        }
    }

    // value-folding reduction: lane bit m selects which half survives.
    // After all steps, lane l holds the full 1024-wide dot of value l,
    // where l = (local_row << 4) | j.
#pragma unroll
    for (int m = 32; m >= 1; m >>= 1) {
        bool hi = (lane & m) != 0;
#pragma unroll
        for (int i = 0; i < m; ++i) {
            float send = hi ? v[i] : v[i + m];
            float recv = __shfl_xor(send, m, 64);
            v[i] = (hi ? v[i + m] : v[i]) + recv;
        }
    }

    float t = v[0] + bias[lane & 15];
    off[(size_t)rowBase * 16 + lane] = 1.f / (1.f + expf(-t));
}

// ---------------- Phase 2a: per-chunk sums ----------------
__global__ void chunksum_kernel(const float* __restrict__ x, float* __restrict__ csum) {
    int gid = blockIdx.x * 256 + threadIdx.x;   // 32*8192 threads
    int chunk = gid >> 13;
    int col = gid & 8191;
    const float* xp = x + (size_t)chunk * LT * COLS + col;
    float s = 0.f;
    for (int t = 0; t < LT; ++t) s += xp[(size_t)t * COLS];
    csum[gid] = s * INV_K;
}

// ---------------- Phase 2b: scan within chunk + write S ----------------
__global__ void scan_kernel(const float* __restrict__ x, const float* __restrict__ csum,
                            float* __restrict__ S) {
    int gid = blockIdx.x * 256 + threadIdx.x;
    int chunk = gid >> 13;                      // uniform within block
    int col = gid & 8191;
    float run = 0.f;
    for (int c = 0; c < chunk; ++c) run += csum[c * COLS + col];  // L2-hot, 1MB
    const float* xp = x + (size_t)chunk * LT * COLS + col;
    float* Sp = S + (size_t)chunk * LT * COLS + col;
    for (int t = 0; t < LT; ++t) {
        run += xp[(size_t)t * COLS] * INV_K;
        Sp[(size_t)t * COLS] = run;             // coalesced
    }
}

// ---------------- Phase 3: interpolated gather ----------------
__device__ __forceinline__ float interp1(const float* __restrict__ S, float f, int col) {
    float ff = floorf(f);
    int i0 = (int)ff;
    float frac = f - ff;
    int i0c = min(max(i0, 0), T_DIM - 1);
    int i1c = min(i0 + 1, T_DIM - 1);           // i0+1 >= 0 since f >= -1
    float v1 = S[(size_t)i1c * COLS + col];
    float v0 = (i0 >= 0) ? S[(size_t)i0c * COLS + col] : 0.f;
    return v0 + frac * (v1 - v0);
}

__global__ void gather_kernel(const float* __restrict__ S, const float* __restrict__ off,
                              float* __restrict__ out) {
    int idx = blockIdx.x * 256 + threadIdx.x;   // < T*B*C
    int r = idx & 127;
    int bh = (idx >> 7) & 63;
    int t = idx >> 13;
    int b = bh >> 3, h = bh & 7;
    const float* o = off + ((size_t)t * B_DIM + b) * 16;
    float aL = o[h], aR = o[8 + h];
    float tf = (float)t;
    float lenL = 1.f + aL * fmaxf(tf - 1.f, 0.f);
    float lenR = 1.f + aR * fmaxf((float)(T_DIM - 1) - tf - 1.f, 0.f);
    float fL = fmaxf(tf - lenL - 1.f, -1.f);
    float fR = fminf(tf + lenR, (float)(T_DIM - 1));
    int col = (bh << 7) | r;
    out[idx] = interp1(S, fR, col) - interp1(S, fL, col);
}

extern "C" void kernel_launch(void* const* d_in, const int* in_sizes, int n_in,
                              void* d_out, int out_size, void* d_ws, size_t ws_size,
                              hipStream_t stream) {
    const float* x = (const float*)d_in[0];
    const float* W = (const float*)d_in[1];
    const float* b = (const float*)d_in[2];
    float* out = (float*)d_out;

    char* ws = (char*)d_ws;
    const size_t S_bytes   = (size_t)T_DIM * COLS * sizeof(float);      // 64 MB
    const size_t off_bytes = (size_t)T_DIM * B_DIM * 16 * sizeof(float); // 1 MB
    float* S    = (float*)ws;
    float* off  = (float*)(ws + S_bytes);
    float* csum = (float*)(ws + S_bytes + off_bytes);                    // 1 MB

    offsets_kernel<<<(T_DIM * B_DIM) / 16, 256, 0, stream>>>(x, W, b, off);
    chunksum_kernel<<<(NCH * COLS) / 256, 256, 0, stream>>>(x, csum);
    scan_kernel<<<(NCH * COLS) / 256, 256, 0, stream>>>(x, csum, S);
    gather_kernel<<<(T_DIM * B_DIM * C_DIM) / 256, 256, 0, stream>>>(S, off, out);
}

// Round 3
// 98.183 us; speedup vs baseline: 3.2134x; 1.1144x over previous
//
#include <hip/hip_runtime.h>
#include <cmath>

#define T_DIM 2048
#define B_DIM 8
#define C_DIM 1024
#define H_DIM 8
#define R_DIM 128
#define BH_DIM 64          // B*H
#define COLS 8192          // BH*R
#define COL4 2048          // COLS/4
#define NCH 64             // scan chunks
#define LT 32              // T per chunk
__device__ __constant__ float INV_K = 0.33333333333333333f;

// ---------------- Phase 1: off = sigmoid(x @ W + b) ----------------
// 4 waves/block, 4 rows per wave processed CONCURRENTLY (see round 1 notes).
__global__ __launch_bounds__(256) void offsets_kernel(
        const float* __restrict__ x, const float* __restrict__ W,
        const float* __restrict__ bias, float* __restrict__ off) {
    __shared__ float Wt[16 * 1024];
    for (int idx = threadIdx.x; idx < 4096; idx += 256) {
        int c = idx >> 2, j4 = (idx & 3) * 4;
        float4 w = *reinterpret_cast<const float4*>(W + c * 16 + j4);
        Wt[(j4 + 0) * 1024 + c] = w.x;
        Wt[(j4 + 1) * 1024 + c] = w.y;
        Wt[(j4 + 2) * 1024 + c] = w.z;
        Wt[(j4 + 3) * 1024 + c] = w.w;
    }
    __syncthreads();

    int wave = threadIdx.x >> 6, lane = threadIdx.x & 63;
    int rowBase = blockIdx.x * 16 + wave * 4;
    const float* xr = x + (size_t)rowBase * C_DIM;

    float v[64];
#pragma unroll
    for (int i = 0; i < 64; ++i) v[i] = 0.f;

#pragma unroll
    for (int k = 0; k < 4; ++k) {
        int c = lane * 4 + k * 256;
        float4 xa = *reinterpret_cast<const float4*>(xr + c);
        float4 xb = *reinterpret_cast<const float4*>(xr + 1024 + c);
        float4 xc = *reinterpret_cast<const float4*>(xr + 2048 + c);
        float4 xd = *reinterpret_cast<const float4*>(xr + 3072 + c);
#pragma unroll
        for (int j = 0; j < 16; ++j) {
            float4 w = *reinterpret_cast<const float4*>(&Wt[j * 1024 + c]);
            v[j]      = fmaf(xa.x, w.x, fmaf(xa.y, w.y, fmaf(xa.z, w.z, fmaf(xa.w, w.w, v[j]))));
            v[16 + j] = fmaf(xb.x, w.x, fmaf(xb.y, w.y, fmaf(xb.z, w.z, fmaf(xb.w, w.w, v[16 + j]))));
            v[32 + j] = fmaf(xc.x, w.x, fmaf(xc.y, w.y, fmaf(xc.z, w.z, fmaf(xc.w, w.w, v[32 + j]))));
            v[48 + j] = fmaf(xd.x, w.x, fmaf(xd.y, w.y, fmaf(xd.z, w.z, fmaf(xd.w, w.w, v[48 + j]))));
        }
    }

#pragma unroll
    for (int m = 32; m >= 1; m >>= 1) {
        bool hi = (lane & m) != 0;
#pragma unroll
        for (int i = 0; i < m; ++i) {
            float send = hi ? v[i] : v[i + m];
            float recv = __shfl_xor(send, m, 64);
            v[i] = (hi ? v[i + m] : v[i]) + recv;
        }
    }

    float t = v[0] + bias[lane & 15];
    off[(size_t)rowBase * 16 + lane] = 1.f / (1.f + expf(-t));
}

// ---------------- Phase 2a: per-chunk column sums (float4) ----------------
__global__ void chunksum_kernel(const float4* __restrict__ x4, float4* __restrict__ csum4) {
    int gid = blockIdx.x * 256 + threadIdx.x;   // NCH * COL4 threads
    int chunk = gid >> 11;
    int col4 = gid & (COL4 - 1);
    const float4* xp = x4 + (size_t)chunk * LT * COL4 + col4;
    float sx = 0.f, sy = 0.f, sz = 0.f, sw = 0.f;
#pragma unroll 4
    for (int t = 0; t < LT; ++t) {
        float4 v = xp[(size_t)t * COL4];
        sx += v.x; sy += v.y; sz += v.z; sw += v.w;
    }
    float4 r; r.x = sx * INV_K; r.y = sy * INV_K; r.z = sz * INV_K; r.w = sw * INV_K;
    csum4[gid] = r;
}

// ---------------- Phase 2b: scan within chunk + write S (float4) ----------------
__global__ void scan_kernel(const float4* __restrict__ x4, const float4* __restrict__ csum4,
                            float4* __restrict__ S4) {
    int gid = blockIdx.x * 256 + threadIdx.x;
    int chunk = gid >> 11;                      // uniform within block
    int col4 = gid & (COL4 - 1);
    float rx = 0.f, ry = 0.f, rz = 0.f, rw = 0.f;
    for (int c = 0; c < chunk; ++c) {           // csum is 2MB -> L2-hot
        float4 v = csum4[c * COL4 + col4];
        rx += v.x; ry += v.y; rz += v.z; rw += v.w;
    }
    const float4* xp = x4 + (size_t)chunk * LT * COL4 + col4;
    float4* Sp = S4 + (size_t)chunk * LT * COL4 + col4;
#pragma unroll 4
    for (int t = 0; t < LT; ++t) {
        float4 v = xp[(size_t)t * COL4];
        rx = fmaf(v.x, INV_K, rx);
        ry = fmaf(v.y, INV_K, ry);
        rz = fmaf(v.z, INV_K, rz);
        rw = fmaf(v.w, INV_K, rw);
        float4 o; o.x = rx; o.y = ry; o.z = rz; o.w = rw;
        Sp[(size_t)t * COL4] = o;               // coalesced 16B/lane
    }
}

// ---------------- Phase 3: interpolated gather (float4) ----------------
__global__ void gather_kernel(const float* __restrict__ S, const float* __restrict__ off,
                              float4* __restrict__ out4) {
    int vid = blockIdx.x * 256 + threadIdx.x;   // T*B*C/4 vec elements
    int r4 = (vid & 31) << 2;
    int bh = (vid >> 5) & 63;
    int t = vid >> 11;                          // uniform per block
    int b = bh >> 3, h = bh & 7;
    const float* o = off + ((size_t)t * B_DIM + b) * 16;
    float aL = o[h], aR = o[8 + h];
    float tf = (float)t;
    float lenL = 1.f + aL * fmaxf(tf - 1.f, 0.f);
    float lenR = 1.f + aR * fmaxf((float)(T_DIM - 1) - tf - 1.f, 0.f);
    float fL = fmaxf(tf - lenL - 1.f, -1.f);
    float fR = fminf(tf + lenR, (float)(T_DIM - 1));
    int col = (bh << 7) | r4;

    float ffL = floorf(fL); int i0L = (int)ffL; float frL = fL - ffL;
    float ffR = floorf(fR); int i0R = (int)ffR; float frR = fR - ffR;
    int i0Lc = min(max(i0L, 0), T_DIM - 1), i1Lc = min(i0L + 1, T_DIM - 1);
    int i0Rc = min(max(i0R, 0), T_DIM - 1), i1Rc = min(i0R + 1, T_DIM - 1);

    const float4 zero4 = {0.f, 0.f, 0.f, 0.f};
    float4 v1L = *reinterpret_cast<const float4*>(S + (size_t)i1Lc * COLS + col);
    float4 v0L = (i0L >= 0) ? *reinterpret_cast<const float4*>(S + (size_t)i0Lc * COLS + col) : zero4;
    float4 v1R = *reinterpret_cast<const float4*>(S + (size_t)i1Rc * COLS + col);
    float4 v0R = (i0R >= 0) ? *reinterpret_cast<const float4*>(S + (size_t)i0Rc * COLS + col) : zero4;

    float4 res;
    res.x = fmaf(frR, v1R.x - v0R.x, v0R.x) - fmaf(frL, v1L.x - v0L.x, v0L.x);
    res.y = fmaf(frR, v1R.y - v0R.y, v0R.y) - fmaf(frL, v1L.y - v0L.y, v0L.y);
    res.z = fmaf(frR, v1R.z - v0R.z, v0R.z) - fmaf(frL, v1L.z - v0L.z, v0L.z);
    res.w = fmaf(frR, v1R.w - v0R.w, v0R.w) - fmaf(frL, v1L.w - v0L.w, v0L.w);
    out4[vid] = res;
}

extern "C" void kernel_launch(void* const* d_in, const int* in_sizes, int n_in,
                              void* d_out, int out_size, void* d_ws, size_t ws_size,
                              hipStream_t stream) {
    const float* x = (const float*)d_in[0];
    const float* W = (const float*)d_in[1];
    const float* b = (const float*)d_in[2];

    char* ws = (char*)d_ws;
    const size_t S_bytes   = (size_t)T_DIM * COLS * sizeof(float);       // 64 MB
    const size_t off_bytes = (size_t)T_DIM * B_DIM * 16 * sizeof(float); // 1 MB
    float* S    = (float*)ws;
    float* off  = (float*)(ws + S_bytes);
    float* csum = (float*)(ws + S_bytes + off_bytes);                    // 2 MB

    offsets_kernel<<<(T_DIM * B_DIM) / 16, 256, 0, stream>>>(x, W, b, off);
    chunksum_kernel<<<(NCH * COL4) / 256, 256, 0, stream>>>(
        (const float4*)x, (float4*)csum);
    scan_kernel<<<(NCH * COL4) / 256, 256, 0, stream>>>(
        (const float4*)x, (const float4*)csum, (float4*)S);
    gather_kernel<<<(T_DIM * B_DIM * C_DIM / 4) / 256, 256, 0, stream>>>(
        S, off, (float4*)d_out);
}

// Round 4
// 82.853 us; speedup vs baseline: 3.8080x; 1.1850x over previous
//
#include <hip/hip_runtime.h>
#include <cmath>

#define T_DIM 2048
#define B_DIM 8
#define C_DIM 1024
#define H_DIM 8
#define R_DIM 128
#define BH_DIM 64          // B*H
#define COLS 8192          // BH*R
#define COL4 2048          // COLS/4
#define NCH 64             // scan chunks
#define LT 32              // T per chunk
__device__ __constant__ float INV_K = 0.33333333333333333f;

typedef _Float16 h4 __attribute__((ext_vector_type(4)));
typedef _Float16 h8 __attribute__((ext_vector_type(8)));

// ---------------- Phase 1: off = sigmoid(x @ W + b) ----------------
// 4 waves/block, 4 rows per wave processed CONCURRENTLY (see round 1 notes).
__global__ __launch_bounds__(256) void offsets_kernel(
        const float* __restrict__ x, const float* __restrict__ W,
        const float* __restrict__ bias, float* __restrict__ off) {
    __shared__ float Wt[16 * 1024];
    for (int idx = threadIdx.x; idx < 4096; idx += 256) {
        int c = idx >> 2, j4 = (idx & 3) * 4;
        float4 w = *reinterpret_cast<const float4*>(W + c * 16 + j4);
        Wt[(j4 + 0) * 1024 + c] = w.x;
        Wt[(j4 + 1) * 1024 + c] = w.y;
        Wt[(j4 + 2) * 1024 + c] = w.z;
        Wt[(j4 + 3) * 1024 + c] = w.w;
    }
    __syncthreads();

    int wave = threadIdx.x >> 6, lane = threadIdx.x & 63;
    int rowBase = blockIdx.x * 16 + wave * 4;
    const float* xr = x + (size_t)rowBase * C_DIM;

    float v[64];
#pragma unroll
    for (int i = 0; i < 64; ++i) v[i] = 0.f;

#pragma unroll
    for (int k = 0; k < 4; ++k) {
        int c = lane * 4 + k * 256;
        float4 xa = *reinterpret_cast<const float4*>(xr + c);
        float4 xb = *reinterpret_cast<const float4*>(xr + 1024 + c);
        float4 xc = *reinterpret_cast<const float4*>(xr + 2048 + c);
        float4 xd = *reinterpret_cast<const float4*>(xr + 3072 + c);
#pragma unroll
        for (int j = 0; j < 16; ++j) {
            float4 w = *reinterpret_cast<const float4*>(&Wt[j * 1024 + c]);
            v[j]      = fmaf(xa.x, w.x, fmaf(xa.y, w.y, fmaf(xa.z, w.z, fmaf(xa.w, w.w, v[j]))));
            v[16 + j] = fmaf(xb.x, w.x, fmaf(xb.y, w.y, fmaf(xb.z, w.z, fmaf(xb.w, w.w, v[16 + j]))));
            v[32 + j] = fmaf(xc.x, w.x, fmaf(xc.y, w.y, fmaf(xc.z, w.z, fmaf(xc.w, w.w, v[32 + j]))));
            v[48 + j] = fmaf(xd.x, w.x, fmaf(xd.y, w.y, fmaf(xd.z, w.z, fmaf(xd.w, w.w, v[48 + j]))));
        }
    }

#pragma unroll
    for (int m = 32; m >= 1; m >>= 1) {
        bool hi = (lane & m) != 0;
#pragma unroll
        for (int i = 0; i < m; ++i) {
            float send = hi ? v[i] : v[i + m];
            float recv = __shfl_xor(send, m, 64);
            v[i] = (hi ? v[i + m] : v[i]) + recv;
        }
    }

    float t = v[0] + bias[lane & 15];
    off[(size_t)rowBase * 16 + lane] = 1.f / (1.f + expf(-t));
}

// ---------------- Phase 2a: per-chunk column sums (float4) ----------------
__global__ void chunksum_kernel(const float4* __restrict__ x4, float4* __restrict__ csum4) {
    int gid = blockIdx.x * 256 + threadIdx.x;   // NCH * COL4 threads
    int chunk = gid >> 11;
    int col4 = gid & (COL4 - 1);
    const float4* xp = x4 + (size_t)chunk * LT * COL4 + col4;
    float sx = 0.f, sy = 0.f, sz = 0.f, sw = 0.f;
#pragma unroll 4
    for (int t = 0; t < LT; ++t) {
        float4 v = xp[(size_t)t * COL4];
        sx += v.x; sy += v.y; sz += v.z; sw += v.w;
    }
    float4 r; r.x = sx * INV_K; r.y = sy * INV_K; r.z = sz * INV_K; r.w = sw * INV_K;
    csum4[gid] = r;
}

// ---------------- Phase 2b: scan within chunk, fp32 accum, fp16 store ----------------
__global__ void scan_kernel(const float4* __restrict__ x4, const float4* __restrict__ csum4,
                            _Float16* __restrict__ S) {
    int gid = blockIdx.x * 256 + threadIdx.x;
    int chunk = gid >> 11;                      // uniform within block
    int col4 = gid & (COL4 - 1);
    float rx = 0.f, ry = 0.f, rz = 0.f, rw = 0.f;
    for (int c = 0; c < chunk; ++c) {           // csum is 2MB -> L2-hot
        float4 v = csum4[c * COL4 + col4];
        rx += v.x; ry += v.y; rz += v.z; rw += v.w;
    }
    const float4* xp = x4 + (size_t)chunk * LT * COL4 + col4;
    _Float16* Sp = S + (size_t)chunk * LT * COLS + col4 * 4;
#pragma unroll 4
    for (int t = 0; t < LT; ++t) {
        float4 v = xp[(size_t)t * COL4];
        rx = fmaf(v.x, INV_K, rx);
        ry = fmaf(v.y, INV_K, ry);
        rz = fmaf(v.z, INV_K, rz);
        rw = fmaf(v.w, INV_K, rw);
        h4 o; o.x = (_Float16)rx; o.y = (_Float16)ry; o.z = (_Float16)rz; o.w = (_Float16)rw;
        *reinterpret_cast<h4*>(Sp + (size_t)t * COLS) = o;   // coalesced 8B/lane
    }
}

// ---------------- Phase 3: interpolated gather (fp16 S, 8 out/thread) ----------------
__global__ void gather_kernel(const _Float16* __restrict__ S, const float* __restrict__ off,
                              float* __restrict__ out) {
    int vid = blockIdx.x * 256 + threadIdx.x;   // T*B*C/8 vec elements
    int r8 = (vid & 15) << 3;
    int bh = (vid >> 4) & 63;
    int t = vid >> 10;
    int b = bh >> 3, h = bh & 7;
    const float* o = off + ((size_t)t * B_DIM + b) * 16;
    float aL = o[h], aR = o[8 + h];
    float tf = (float)t;
    float lenL = 1.f + aL * fmaxf(tf - 1.f, 0.f);
    float lenR = 1.f + aR * fmaxf((float)(T_DIM - 1) - tf - 1.f, 0.f);
    float fL = fmaxf(tf - lenL - 1.f, -1.f);
    float fR = fminf(tf + lenR, (float)(T_DIM - 1));
    int col = (bh << 7) | r8;

    float ffL = floorf(fL); int i0L = (int)ffL; float frL = fL - ffL;
    float ffR = floorf(fR); int i0R = (int)ffR; float frR = fR - ffR;
    int i0Lc = min(max(i0L, 0), T_DIM - 1), i1Lc = min(i0L + 1, T_DIM - 1);
    int i0Rc = min(max(i0R, 0), T_DIM - 1), i1Rc = min(i0R + 1, T_DIM - 1);

    const h8 zero8 = {0, 0, 0, 0, 0, 0, 0, 0};
    h8 v1L = *reinterpret_cast<const h8*>(S + (size_t)i1Lc * COLS + col);
    h8 v0L = (i0L >= 0) ? *reinterpret_cast<const h8*>(S + (size_t)i0Lc * COLS + col) : zero8;
    h8 v1R = *reinterpret_cast<const h8*>(S + (size_t)i1Rc * COLS + col);
    h8 v0R = (i0R >= 0) ? *reinterpret_cast<const h8*>(S + (size_t)i0Rc * COLS + col) : zero8;

    float res[8];
#pragma unroll
    for (int i = 0; i < 8; ++i) {
        float a0 = (float)v0R[i], a1 = (float)v1R[i];
        float b0 = (float)v0L[i], b1 = (float)v1L[i];
        res[i] = fmaf(frR, a1 - a0, a0) - fmaf(frL, b1 - b0, b0);
    }
    float* op = out + (size_t)vid * 8;
    *reinterpret_cast<float4*>(op)     = make_float4(res[0], res[1], res[2], res[3]);
    *reinterpret_cast<float4*>(op + 4) = make_float4(res[4], res[5], res[6], res[7]);
}

extern "C" void kernel_launch(void* const* d_in, const int* in_sizes, int n_in,
                              void* d_out, int out_size, void* d_ws, size_t ws_size,
                              hipStream_t stream) {
    const float* x = (const float*)d_in[0];
    const float* W = (const float*)d_in[1];
    const float* b = (const float*)d_in[2];

    char* ws = (char*)d_ws;
    const size_t S_bytes   = (size_t)T_DIM * COLS * sizeof(_Float16);    // 32 MB
    const size_t off_bytes = (size_t)T_DIM * B_DIM * 16 * sizeof(float); // 1 MB
    _Float16* S = (_Float16*)ws;
    float* off  = (float*)(ws + S_bytes);
    float* csum = (float*)(ws + S_bytes + off_bytes);                    // 2 MB

    offsets_kernel<<<(T_DIM * B_DIM) / 16, 256, 0, stream>>>(x, W, b, off);
    chunksum_kernel<<<(NCH * COL4) / 256, 256, 0, stream>>>(
        (const float4*)x, (float4*)csum);
    scan_kernel<<<(NCH * COL4) / 256, 256, 0, stream>>>(
        (const float4*)x, (const float4*)csum, S);
    gather_kernel<<<(T_DIM * B_DIM * C_DIM / 8) / 256, 256, 0, stream>>>(
        S, off, (float*)d_out);
}

// Round 6
// 77.782 us; speedup vs baseline: 4.0562x; 1.0652x over previous
//
#include <hip/hip_runtime.h>
#include <cmath>

#define T_DIM 2048
#define B_DIM 8
#define C_DIM 1024
#define H_DIM 8
#define R_DIM 128
#define BH_DIM 64          // B*H
#define COLS 8192          // BH*R
#define COL4 2048          // COLS/4
#define NCH 64             // scan chunks
#define LT 32              // T per chunk
__device__ __constant__ float INV_K = 0.33333333333333333f;

typedef _Float16 h4 __attribute__((ext_vector_type(4)));
typedef _Float16 h8 __attribute__((ext_vector_type(8)));

// ---- Kernel A: fused offsets GEMM + per-chunk column sums (ONE x read) ----
// Grid 512 = 8 col-groups (== batch b) x 64 t-chunks. Block (cg, ch) streams
// x[t, b=cg, :] for 32 t's, 4 t's at a time (xv[4], discarded after use):
//   - offsets GEMM partials (Wt in LDS, validated 64-value wave fold)
//   - per-chunk column sums -> csum4
// No grid sync needed: scan (kernel B) runs as a separate dispatch.
__global__ __launch_bounds__(256, 2) void offcsum_kernel(
        const float4* __restrict__ x4, const float* __restrict__ W,
        const float* __restrict__ bias, float* __restrict__ off,
        float4* __restrict__ csum4) {
    __shared__ float Wt[16 * 1024];          // 64 KB
    __shared__ float sdata[4][8][64];        // 8 KB
    const int bid = blockIdx.x;
    const int cg = bid >> 6;                 // 0..7  == batch index b
    const int ch = bid & 63;                 // 0..63 == t chunk
    const int tid = threadIdx.x;
    const int wave = tid >> 6, lane = tid & 63;
    const int col4 = cg * 256 + tid;         // global col4 in [0, 2048)

    for (int idx = tid; idx < 4096; idx += 256) {
        int c = idx >> 2, j4 = (idx & 3) * 4;
        float4 w = *reinterpret_cast<const float4*>(W + c * 16 + j4);
        Wt[(j4 + 0) * 1024 + c] = w.x;
        Wt[(j4 + 1) * 1024 + c] = w.y;
        Wt[(j4 + 2) * 1024 + c] = w.z;
        Wt[(j4 + 3) * 1024 + c] = w.w;
    }
    __syncthreads();

    const float4* xp = x4 + (size_t)(ch * LT) * COL4 + col4;
    const int cbase = tid * 4;
    float csx = 0.f, csy = 0.f, csz = 0.f, csw = 0.f;

#pragma unroll 1
    for (int g = 0; g < 8; ++g) {
        float4 xv0 = xp[(size_t)(g * 4 + 0) * COL4];
        float4 xv1 = xp[(size_t)(g * 4 + 1) * COL4];
        float4 xv2 = xp[(size_t)(g * 4 + 2) * COL4];
        float4 xv3 = xp[(size_t)(g * 4 + 3) * COL4];
        float acc[64];
#pragma unroll
        for (int i = 0; i < 64; ++i) acc[i] = 0.f;
#pragma unroll
        for (int j = 0; j < 16; ++j) {
            float4 w = *reinterpret_cast<const float4*>(&Wt[j * 1024 + cbase]);
            acc[j]      = fmaf(xv0.x, w.x, fmaf(xv0.y, w.y, fmaf(xv0.z, w.z, fmaf(xv0.w, w.w, acc[j]))));
            acc[16 + j] = fmaf(xv1.x, w.x, fmaf(xv1.y, w.y, fmaf(xv1.z, w.z, fmaf(xv1.w, w.w, acc[16 + j]))));
            acc[32 + j] = fmaf(xv2.x, w.x, fmaf(xv2.y, w.y, fmaf(xv2.z, w.z, fmaf(xv2.w, w.w, acc[32 + j]))));
            acc[48 + j] = fmaf(xv3.x, w.x, fmaf(xv3.y, w.y, fmaf(xv3.z, w.z, fmaf(xv3.w, w.w, acc[48 + j]))));
        }
        csx += xv0.x + xv1.x + xv2.x + xv3.x;
        csy += xv0.y + xv1.y + xv2.y + xv3.y;
        csz += xv0.z + xv1.z + xv2.z + xv3.z;
        csw += xv0.w + xv1.w + xv2.w + xv3.w;
        // value-folding wave reduction: lane l ends with value (tl<<4)|j
#pragma unroll
        for (int m = 32; m >= 1; m >>= 1) {
            bool hi = (lane & m) != 0;
#pragma unroll
            for (int i = 0; i < m; ++i) {
                float send = hi ? acc[i] : acc[i + m];
                float recv = __shfl_xor(send, m, 64);
                acc[i] = (hi ? acc[i + m] : acc[i]) + recv;
            }
        }
        sdata[wave][g][lane] = acc[0];
    }

    float4 agg; agg.x = csx * INV_K; agg.y = csy * INV_K; agg.z = csz * INV_K; agg.w = csw * INV_K;
    csum4[(size_t)ch * COL4 + col4] = agg;

    __syncthreads();
    // cross-wave reduce (sum the four 256-col partials) + off write
#pragma unroll
    for (int i = 0; i < 2; ++i) {
        int idx = tid + i * 256;
        int g = idx >> 6, l = idx & 63;
        int tl = l >> 4, j = l & 15;
        float s = sdata[0][g][l] + sdata[1][g][l] + sdata[2][g][l] + sdata[3][g][l];
        s += bias[j];
        int t = ch * LT + g * 4 + tl;
        off[((size_t)t * B_DIM + cg) * 16 + j] = 1.f / (1.f + expf(-s));
    }
}

// ---- Kernel B: scan within chunk, fp32 accum, fp16 store (round-4 proven) ----
__global__ void scan_kernel(const float4* __restrict__ x4, const float4* __restrict__ csum4,
                            _Float16* __restrict__ S) {
    int gid = blockIdx.x * 256 + threadIdx.x;
    int chunk = gid >> 11;                      // uniform within block
    int col4 = gid & (COL4 - 1);
    float rx = 0.f, ry = 0.f, rz = 0.f, rw = 0.f;
    for (int c = 0; c < chunk; ++c) {           // csum is 2MB -> L2-hot
        float4 v = csum4[c * COL4 + col4];
        rx += v.x; ry += v.y; rz += v.z; rw += v.w;
    }
    const float4* xp = x4 + (size_t)chunk * LT * COL4 + col4;
    _Float16* Sp = S + (size_t)chunk * LT * COLS + col4 * 4;
#pragma unroll 4
    for (int t = 0; t < LT; ++t) {
        float4 v = xp[(size_t)t * COL4];
        rx = fmaf(v.x, INV_K, rx);
        ry = fmaf(v.y, INV_K, ry);
        rz = fmaf(v.z, INV_K, rz);
        rw = fmaf(v.w, INV_K, rw);
        h4 o; o.x = (_Float16)rx; o.y = (_Float16)ry; o.z = (_Float16)rz; o.w = (_Float16)rw;
        *reinterpret_cast<h4*>(Sp + (size_t)t * COLS) = o;   // coalesced 8B/lane
    }
}

// ---- Kernel C: interpolated gather (fp16 S, 8 out/thread, XCD swizzle) ----
__global__ void gather_kernel(const _Float16* __restrict__ S, const float* __restrict__ off,
                              float* __restrict__ out) {
    // bijective XCD swizzle (8192 % 8 == 0): XCD x gets a contiguous t-range
    int bid = blockIdx.x;
    int sbid = (bid & 7) * 1024 + (bid >> 3);
    int vid = sbid * 256 + threadIdx.x;         // T*B*C/8 vec elements
    int r8 = (vid & 15) << 3;
    int bh = (vid >> 4) & 63;
    int t = vid >> 10;
    int b = bh >> 3, h = bh & 7;
    const float* o = off + ((size_t)t * B_DIM + b) * 16;
    float aL = o[h], aR = o[8 + h];
    float tf = (float)t;
    float lenL = 1.f + aL * fmaxf(tf - 1.f, 0.f);
    float lenR = 1.f + aR * fmaxf((float)(T_DIM - 1) - tf - 1.f, 0.f);
    float fL = fmaxf(tf - lenL - 1.f, -1.f);
    float fR = fminf(tf + lenR, (float)(T_DIM - 1));
    int col = (bh << 7) | r8;

    float ffL = floorf(fL); int i0L = (int)ffL; float frL = fL - ffL;
    float ffR = floorf(fR); int i0R = (int)ffR; float frR = fR - ffR;
    int i0Lc = min(max(i0L, 0), T_DIM - 1), i1Lc = min(i0L + 1, T_DIM - 1);
    int i0Rc = min(max(i0R, 0), T_DIM - 1), i1Rc = min(i0R + 1, T_DIM - 1);

    const h8 zero8 = {0, 0, 0, 0, 0, 0, 0, 0};
    h8 v1L = *reinterpret_cast<const h8*>(S + (size_t)i1Lc * COLS + col);
    h8 v0L = (i0L >= 0) ? *reinterpret_cast<const h8*>(S + (size_t)i0Lc * COLS + col) : zero8;
    h8 v1R = *reinterpret_cast<const h8*>(S + (size_t)i1Rc * COLS + col);
    h8 v0R = (i0R >= 0) ? *reinterpret_cast<const h8*>(S + (size_t)i0Rc * COLS + col) : zero8;

    float res[8];
#pragma unroll
    for (int i = 0; i < 8; ++i) {
        float a0 = (float)v0R[i], a1 = (float)v1R[i];
        float b0 = (float)v0L[i], b1 = (float)v1L[i];
        res[i] = fmaf(frR, a1 - a0, a0) - fmaf(frL, b1 - b0, b0);
    }
    float* op = out + (size_t)vid * 8;
    *reinterpret_cast<float4*>(op)     = make_float4(res[0], res[1], res[2], res[3]);
    *reinterpret_cast<float4*>(op + 4) = make_float4(res[4], res[5], res[6], res[7]);
}

extern "C" void kernel_launch(void* const* d_in, const int* in_sizes, int n_in,
                              void* d_out, int out_size, void* d_ws, size_t ws_size,
                              hipStream_t stream) {
    const float4* x4 = (const float4*)d_in[0];
    const float* W  = (const float*)d_in[1];
    const float* bi = (const float*)d_in[2];

    char* ws = (char*)d_ws;
    const size_t S_bytes   = (size_t)T_DIM * COLS * sizeof(_Float16);    // 32 MB
    const size_t off_bytes = (size_t)T_DIM * B_DIM * 16 * sizeof(float); // 1 MB
    _Float16* S = (_Float16*)ws;
    float* off  = (float*)(ws + S_bytes);
    float* csum = (float*)(ws + S_bytes + off_bytes);                    // 2 MB

    offcsum_kernel<<<512, 256, 0, stream>>>(x4, W, bi, off, (float4*)csum);
    scan_kernel<<<(NCH * COL4) / 256, 256, 0, stream>>>(
        x4, (const float4*)csum, S);
    gather_kernel<<<(T_DIM * B_DIM * C_DIM / 8) / 256, 256, 0, stream>>>(
        S, off, (float*)d_out);
}